// Round 6
// baseline (4663.491 us; speedup 1.0000x reference)
//
#include <hip/hip_runtime.h>
#include <cstdint>
#include <cstddef>

// ---------------------------------------------------------------------------
// LSTM  B=64, T=1024, D=H=512.
//   * xcvt: x_seq fp32 -> fp16 in ws (one-time).
//   * lstm_rec: persistent, 256 WGs = 8 batch-groups x 32 column-groups.
//     WG (g,c): batch rows g*8..g*8+7, hidden units c*16..c*16+15.
//     Wh & Wx slices LDS-resident fp16 (133 KB, 1 WG/CU).
//     Tagged self-sync h at agent scope (sc1) — the R3-proven semantics.
//     R4/R5's sc0-only "XCD-L2 coherence" fast path HUNG twice: sc0-only
//     cross-CU handoff is outside the architected memory model (no XCD
//     scope; consumer L1 can hold stale lines). Reverted permanently.
//     R6: TWO-PHASE SENTINEL POLL to kill MALL poll-BW congestion:
//       phase 1: wave 0's 64 lanes spin on 2 sentinel tagged words per
//                producer (128 B/pass vs 16 KB/pass — 128x less traffic);
//       phase 2: all 256 threads bulk-load the 16 KB payload once, verify
//                EVERY word's tag, retry only stale words (tags make
//                partial arrival safe; no acks anywhere).
// ---------------------------------------------------------------------------

typedef _Float16 half8  __attribute__((ext_vector_type(8)));
typedef _Float16 half4v __attribute__((ext_vector_type(4)));
typedef float    float4v __attribute__((ext_vector_type(4)));

__device__ __forceinline__ float sigm(float x) { return 1.f / (1.f + __expf(-x)); }
__device__ __forceinline__ float tanh_f(float x) { return 2.f / (1.f + __expf(-2.f * x)) - 1.f; }

// ----------------------------- x fp32 -> fp16 ------------------------------
__global__ __launch_bounds__(256) void xcvt(const float* __restrict__ X,
                                            _Float16* __restrict__ XH) {
    size_t i = ((size_t)blockIdx.x * 256 + threadIdx.x) * 8;
    float4 a = *(const float4*)(X + i);
    float4 b = *(const float4*)(X + i + 4);
    half8 v;
    v[0] = (_Float16)a.x; v[1] = (_Float16)a.y; v[2] = (_Float16)a.z; v[3] = (_Float16)a.w;
    v[4] = (_Float16)b.x; v[5] = (_Float16)b.y; v[6] = (_Float16)b.z; v[7] = (_Float16)b.w;
    *(half8*)(XH + i) = v;
}

// ------------------------------- recurrence --------------------------------
__global__ __launch_bounds__(256, 1) void lstm_rec(
    const float* __restrict__ Whf, const float* __restrict__ Whi,
    const float* __restrict__ Whg, const float* __restrict__ Who,
    const float* __restrict__ Wxf, const float* __restrict__ Wxi,
    const float* __restrict__ Wxg, const float* __restrict__ Wxo,
    const float* __restrict__ bxf, const float* __restrict__ bxi,
    const float* __restrict__ bxg, const float* __restrict__ bxo,
    const float* __restrict__ bhf, const float* __restrict__ bhi,
    const float* __restrict__ bhg, const float* __restrict__ bho,
    const _Float16* __restrict__ XH,        // [64][1024][512] fp16
    unsigned long long* __restrict__ hws,   // tagged h [2][8][8][256] u64, zeroed
    float* __restrict__ out)                // [64][512] fp32
{
    const int blk  = blockIdx.x;
    const int g    = blk & 7;    // batch group
    const int c    = blk >> 3;   // column group 0..31
    const int tid  = threadIdx.x;
    const int w    = tid >> 6;   // wave 0..3 -> gate-col tile w*16..w*16+15
    const int lane = tid & 63;
    const int l15  = lane & 15;
    const int quad = lane >> 4;
    const int m    = l15 & 7;    // batch row within group

    __shared__ _Float16 Wls[64][520];  // Wh slice, rows = [f16|i16|g16|o16]
    __shared__ _Float16 Xls[64][520];  // Wx slice, same layout
    __shared__ _Float16 hls[8][520];   // staged h_t payload [row][512 units]
    __shared__ float    gs[8][65];     // gate preacts [row][gatecol]

    // ---- one-time: weight slices -> LDS fp16 ----
    const float* WhSeg[4] = {Whf, Whi, Whg, Who};
    const float* WxSeg[4] = {Wxf, Wxi, Wxg, Wxo};
    for (int e = tid * 4; e < 64 * 512; e += 1024) {
        int row = e >> 9, col = e & 511;
        int seg = row >> 4;
        int srow = c * 16 + (row & 15);
        float4 vh = *(const float4*)(WhSeg[seg] + (size_t)srow * 512 + col);
        float4 vx = *(const float4*)(WxSeg[seg] + (size_t)srow * 512 + col);
        half4v th = {(_Float16)vh.x, (_Float16)vh.y, (_Float16)vh.z, (_Float16)vh.w};
        half4v tx = {(_Float16)vx.x, (_Float16)vx.y, (_Float16)vx.z, (_Float16)vx.w};
        *(half4v*)&Wls[row][col] = th;
        *(half4v*)&Xls[row][col] = tx;
    }
    __syncthreads();

    // ---- elementwise role: wave 0 only, 64 threads x (1 row, 2 units) ----
    const int erow = tid >> 3;        // 0..7  (valid for tid<64)
    const int ep   = tid & 7;         // unit pair 0..7 -> units 2ep, 2ep+1
    float bs[8] = {0.f};
    if (tid < 64) {
        int u0 = c * 16 + 2 * ep, u1 = u0 + 1;
        bs[0] = bxf[u0] + bhf[u0];  bs[4] = bxf[u1] + bhf[u1];
        bs[1] = bxi[u0] + bhi[u0];  bs[5] = bxi[u1] + bhi[u1];
        bs[2] = bxg[u0] + bhg[u0];  bs[6] = bxg[u1] + bhg[u1];
        bs[3] = bxo[u0] + bho[u0];  bs[7] = bxo[u1] + bho[u1];
    }
    float c0s = 0.f, c1s = 0.f;

    // consumer staging role: thread loads 16 tagged u32 (8 u64) of group h
    const int crow = tid >> 5;          // 0..7
    const int ccol = (tid & 31) << 4;   // 0..496

    // ---- x-projection shadow: acc_x for step 0 ----
    const size_t xrow = (size_t)(g * 8 + m) * 1024 * 512 + (size_t)quad * 8;
    half8 xf[16];
#pragma unroll
    for (int kk = 0; kk < 16; kk++) xf[kk] = *(const half8*)(XH + xrow + kk * 32);
    float4v accx = {0.f, 0.f, 0.f, 0.f};
#pragma unroll
    for (int kk = 0; kk < 16; kk++) {
        half8 b = *(const half8*)&Xls[w * 16 + l15][kk * 32 + quad * 8];
        accx = __builtin_amdgcn_mfma_f32_16x16x32_f16(xf[kk], b, accx, 0, 0, 0);
    }

    for (int t = 0; t < 1024; t++) {
        const unsigned long long* gb = hws + (size_t)(t & 1) * 16384
                                     + (size_t)g * 2048;
        const unsigned int Ttag = (unsigned)t << 16;

        // ---- phase 1: sentinel spin (wave 0: 2 tagged words / producer) ----
        if (w == 0) {
            int p = lane & 31;            // producer column-group
            int r = (lane >> 5) * 4;      // sample rows 0 and 4
            const unsigned int* s = (const unsigned int*)(gb + (size_t)r * 256
                                                          + (size_t)p * 8);
            while ((__hip_atomic_load(s, __ATOMIC_RELAXED,
                                      __HIP_MEMORY_SCOPE_AGENT)
                    & 0xFFFF0000u) != Ttag) {}
        }
        __syncthreads();

        // ---- phase 2: bulk load payload once, verify all tags, retry ----
        {
            const unsigned long long* hsrc = gb + (size_t)tid * 8;
            const unsigned long long T64 =
                ((unsigned long long)Ttag) | ((unsigned long long)Ttag << 32);
            unsigned long long q[8];
#pragma unroll
            for (int j = 0; j < 8; j++)
                q[j] = __hip_atomic_load(hsrc + j, __ATOMIC_RELAXED,
                                         __HIP_MEMORY_SCOPE_AGENT);
            for (;;) {
                unsigned long long bad = 0;
#pragma unroll
                for (int j = 0; j < 8; j++)
                    bad |= (q[j] ^ T64) & 0xFFFF0000FFFF0000ULL;
                if (!bad) break;
#pragma unroll
                for (int j = 0; j < 8; j++)
                    if ((q[j] ^ T64) & 0xFFFF0000FFFF0000ULL)
                        q[j] = __hip_atomic_load(hsrc + j, __ATOMIC_RELAXED,
                                                 __HIP_MEMORY_SCOPE_AGENT);
            }
            unsigned int* hd = (unsigned int*)&hls[crow][ccol];
#pragma unroll
            for (int j = 0; j < 8; j++)
                hd[j] = (unsigned int)(q[j] & 0xFFFF) |
                        (((unsigned int)(q[j] >> 32)) << 16);
        }
        __syncthreads();

        // ---- h-GEMM: acc = acc_x + h_t @ Wh_slice^T ----
        float4v acca = accx;
        float4v accb = {0.f, 0.f, 0.f, 0.f};
#pragma unroll
        for (int kk = 0; kk < 16; kk += 2) {
            half8 a0 = *(const half8*)&hls[m][kk * 32 + quad * 8];
            half8 a1 = *(const half8*)&hls[m][(kk + 1) * 32 + quad * 8];
            half8 b0 = *(const half8*)&Wls[w * 16 + l15][kk * 32 + quad * 8];
            half8 b1 = *(const half8*)&Wls[w * 16 + l15][(kk + 1) * 32 + quad * 8];
            acca = __builtin_amdgcn_mfma_f32_16x16x32_f16(a0, b0, acca, 0, 0, 0);
            accb = __builtin_amdgcn_mfma_f32_16x16x32_f16(a1, b1, accb, 0, 0, 0);
        }

        // ---- gate preacts -> LDS (rows 0..7 live in quads 0,1) ----
        if (quad < 2) {
#pragma unroll
            for (int r = 0; r < 4; r++)
                gs[quad * 4 + r][w * 16 + l15] = acca[r] + accb[r];
        }
        __syncthreads();

        // ---- elementwise LSTM update + tagged publish (wave 0 only) ----
        if (tid < 64) {
            float pf0 = gs[erow][2 * ep]      + bs[0];
            float pi0 = gs[erow][2 * ep + 16] + bs[1];
            float pg0 = gs[erow][2 * ep + 32] + bs[2];
            float po0 = gs[erow][2 * ep + 48] + bs[3];
            float pf1 = gs[erow][2 * ep + 1]  + bs[4];
            float pi1 = gs[erow][2 * ep + 17] + bs[5];
            float pg1 = gs[erow][2 * ep + 33] + bs[6];
            float po1 = gs[erow][2 * ep + 49] + bs[7];
            c0s = sigm(pf0) * c0s + sigm(pi0) * tanh_f(pg0);
            c1s = sigm(pf1) * c1s + sigm(pi1) * tanh_f(pg1);
            float hn0 = sigm(po0) * tanh_f(c0s);
            float hn1 = sigm(po1) * tanh_f(c1s);
            union { _Float16 f; unsigned short u; } cv0, cv1;
            cv0.f = (_Float16)hn0; cv1.f = (_Float16)hn1;
            unsigned int tag = (unsigned)(t + 1) << 16;
            unsigned long long qv = (unsigned long long)(tag | cv0.u)
                                  | ((unsigned long long)(tag | cv1.u) << 32);
            unsigned long long* hd = hws + (size_t)((t + 1) & 1) * 16384
                                   + (size_t)g * 2048 + (size_t)erow * 256
                                   + c * 8 + ep;
            __hip_atomic_store(hd, qv, __ATOMIC_RELAXED,
                               __HIP_MEMORY_SCOPE_AGENT);
            if (t == 1023) {
                size_t ob = (size_t)(g * 8 + erow) * 512 + c * 16 + 2 * ep;
                out[ob]     = hn0;
                out[ob + 1] = hn1;
            }
        }

        // ---- shadow x-GEMM for step t+1 (off critical path) ----
        int tn = (t < 1023) ? (t + 1) : 0;
        const _Float16* xp = XH + xrow + (size_t)tn * 512;
#pragma unroll
        for (int kk = 0; kk < 16; kk++) xf[kk] = *(const half8*)(xp + kk * 32);
        float4v ax = {0.f, 0.f, 0.f, 0.f};
#pragma unroll
        for (int kk = 0; kk < 16; kk++) {
            half8 b = *(const half8*)&Xls[w * 16 + l15][kk * 32 + quad * 8];
            ax = __builtin_amdgcn_mfma_f32_16x16x32_f16(xf[kk], b, ax, 0, 0, 0);
        }
        accx = ax;
    }
}

// ------------------------------- launcher ----------------------------------
extern "C" void kernel_launch(void* const* d_in, const int* in_sizes, int n_in,
                              void* d_out, int out_size, void* d_ws, size_t ws_size,
                              hipStream_t stream) {
    const float* X   = (const float*)d_in[0];
    const float* Whf = (const float*)d_in[1];  const float* bhf = (const float*)d_in[2];
    const float* Wxf = (const float*)d_in[3];  const float* bxf = (const float*)d_in[4];
    const float* Whi = (const float*)d_in[5];  const float* bhi = (const float*)d_in[6];
    const float* Wxi = (const float*)d_in[7];  const float* bxi = (const float*)d_in[8];
    const float* Whg = (const float*)d_in[9];  const float* bhg = (const float*)d_in[10];
    const float* Wxg = (const float*)d_in[11]; const float* bxg = (const float*)d_in[12];
    const float* Who = (const float*)d_in[13]; const float* bho = (const float*)d_in[14];
    const float* Wxo = (const float*)d_in[15]; const float* bxo = (const float*)d_in[16];

    // ws layout: [0,256KB) tagged h double buffer | [1MB,65MB) XH fp16
    if (ws_size < (size_t)68157440) return;  // need 65 MiB

    char* ws = (char*)d_ws;
    unsigned long long* hws = (unsigned long long*)ws;
    _Float16*           XH  = (_Float16*)(ws + (1 << 20));
    (void)in_sizes; (void)n_in; (void)out_size;

    hipMemsetAsync(d_ws, 0, 262144, stream);
    xcvt<<<16384, 256, 0, stream>>>(X, XH);
    lstm_rec<<<256, 256, 0, stream>>>(Whf, Whi, Whg, Who, Wxf, Wxi, Wxg, Wxo,
                                      bxf, bxi, bxg, bxo, bhf, bhi, bhg, bho,
                                      XH, hws, (float*)d_out);
}

// Round 7
// 4418.974 us; speedup vs baseline: 1.0553x; 1.0553x over previous
//
#include <hip/hip_runtime.h>
#include <cstdint>
#include <cstddef>

// ---------------------------------------------------------------------------
// LSTM  B=64, T=1024, D=H=512.
//   * xcvt: x_seq fp32 -> fp16 in ws (one-time).
//   * lstm_rec: persistent, 256 WGs = 8 batch-groups x 32 column-groups.
//     WG (g,c): batch rows g*8..g*8+7, hidden units c*16..c*16+15.
//     Wh & Wx slices LDS-resident fp16, tagged self-sync h at agent scope
//     (sc0 sc1 — R3-proven; sc0-only XCD path hung twice, permanently dead;
//     R6 sentinel phase regressed +0.65us/step = +1 serial MALL RT, reverted).
//     R7:
//      (1) spin pass = ONE asm burst (4x global_load_dwordx4 sc0 sc1 +
//          single vmcnt(0)) -> guaranteed 1 MALL RT per poll pass
//          (suspect: 8 separate __hip_atomic_loads serialized to ~8 RT).
//      (2) gate-cols re-owned: wave w holds units w*4..w*4+3 with all 4
//          gates interleaved [u0f,u0i,u0g,u0o,...]; after MFMA each wave
//          shuffle-transposes in quads of 4 lanes, runs elementwise on all
//          lanes, publishes its own units IMMEDIATELY. Deletes the second
//          barrier + gs round-trip; publish issues ~0.3-0.4us earlier.
//          One barrier/step (hls repack -> fragment reads). hls(t+1)
//          overwrite is safe: own spin detect of t+1 requires own WG's
//          publishes ⊇ all own waves finished reading hls(t).
// ---------------------------------------------------------------------------

typedef _Float16 half8  __attribute__((ext_vector_type(8)));
typedef _Float16 half4v __attribute__((ext_vector_type(4)));
typedef float    float4v __attribute__((ext_vector_type(4)));
typedef unsigned int uint4v __attribute__((ext_vector_type(4)));

__device__ __forceinline__ float sigm(float x) { return 1.f / (1.f + __expf(-x)); }
__device__ __forceinline__ float tanh_f(float x) { return 2.f / (1.f + __expf(-2.f * x)) - 1.f; }

// agent-scope (sc0 sc1) u64 store — relaxed, fire-and-forget
__device__ __forceinline__ void st_u64(unsigned long long* p, unsigned long long v) {
    asm volatile("global_store_dwordx2 %0, %1, off sc0 sc1" :: "v"(p), "v"(v) : "memory");
}

// agent-scope 64B burst load, ONE vmcnt(0) for the whole pass
__device__ __forceinline__ void ld_burst64(const void* p, uint4v q[4]) {
    asm volatile(
        "global_load_dwordx4 %[a], %[p], off sc0 sc1\n\t"
        "global_load_dwordx4 %[b], %[p], off offset:16 sc0 sc1\n\t"
        "global_load_dwordx4 %[c], %[p], off offset:32 sc0 sc1\n\t"
        "global_load_dwordx4 %[d], %[p], off offset:48 sc0 sc1\n\t"
        "s_waitcnt vmcnt(0)"
        : [a]"=&v"(q[0]), [b]"=&v"(q[1]), [c]"=&v"(q[2]), [d]"=&v"(q[3])
        : [p]"v"(p) : "memory");
}

// ----------------------------- x fp32 -> fp16 ------------------------------
__global__ __launch_bounds__(256) void xcvt(const float* __restrict__ X,
                                            _Float16* __restrict__ XH) {
    size_t i = ((size_t)blockIdx.x * 256 + threadIdx.x) * 8;
    float4 a = *(const float4*)(X + i);
    float4 b = *(const float4*)(X + i + 4);
    half8 v;
    v[0] = (_Float16)a.x; v[1] = (_Float16)a.y; v[2] = (_Float16)a.z; v[3] = (_Float16)a.w;
    v[4] = (_Float16)b.x; v[5] = (_Float16)b.y; v[6] = (_Float16)b.z; v[7] = (_Float16)b.w;
    *(half8*)(XH + i) = v;
}

// ------------------------------- recurrence --------------------------------
__global__ __launch_bounds__(256, 1) void lstm_rec(
    const float* __restrict__ Whf, const float* __restrict__ Whi,
    const float* __restrict__ Whg, const float* __restrict__ Who,
    const float* __restrict__ Wxf, const float* __restrict__ Wxi,
    const float* __restrict__ Wxg, const float* __restrict__ Wxo,
    const float* __restrict__ bxf, const float* __restrict__ bxi,
    const float* __restrict__ bxg, const float* __restrict__ bxo,
    const float* __restrict__ bhf, const float* __restrict__ bhi,
    const float* __restrict__ bhg, const float* __restrict__ bho,
    const _Float16* __restrict__ XH,        // [64][1024][512] fp16
    unsigned long long* __restrict__ hws,   // tagged h [2][8][512][4] u64, zeroed
    float* __restrict__ out)                // [64][512] fp32
{
    const int blk  = blockIdx.x;
    const int g    = blk & 7;    // batch group
    const int c    = blk >> 3;   // column group 0..31 (units c*16..c*16+15)
    const int tid  = threadIdx.x;
    const int w    = tid >> 6;   // wave 0..3 -> units c*16+w*4 .. +3
    const int lane = tid & 63;
    const int l15  = lane & 15;
    const int quad = lane >> 4;
    const int m    = l15 & 7;    // batch row (A-frag; rows 8..15 dup 0..7)

    // gate-col layout per WG (64 cols): col r = wave(r>>4), within-wave l15:
    //   unit_local = (r>>2)&3 (i.e. (l15)>>2), gate = r&3  -> [u0f,u0i,u0g,u0o,u1f,...]
    __shared__ _Float16 Wls[64][520];  // Wh slice in gate-col layout
    __shared__ _Float16 Xls[64][520];  // Wx slice, same layout
    __shared__ _Float16 hls[8][520];   // staged h_t [row][512 units]

    // ---- one-time: weight slices -> LDS fp16 (interleaved layout) ----
    const float* WhSeg[4] = {Whf, Whi, Whg, Who};
    const float* WxSeg[4] = {Wxf, Wxi, Wxg, Wxo};
    for (int e = tid * 4; e < 64 * 512; e += 1024) {
        int row = e >> 9, col = e & 511;
        int gate = row & 3;
        int srow = c * 16 + ((row >> 4) << 2) + ((row >> 2) & 3);
        float4 vh = *(const float4*)(WhSeg[gate] + (size_t)srow * 512 + col);
        float4 vx = *(const float4*)(WxSeg[gate] + (size_t)srow * 512 + col);
        half4v th = {(_Float16)vh.x, (_Float16)vh.y, (_Float16)vh.z, (_Float16)vh.w};
        half4v tx = {(_Float16)vx.x, (_Float16)vx.y, (_Float16)vx.z, (_Float16)vx.w};
        *(half4v*)&Wls[row][col] = th;
        *(half4v*)&Xls[row][col] = tx;
    }
    __syncthreads();

    // ---- per-lane bias (own gate-col): gate = l15&3, unit = c*16+w*4+(l15>>2)
    const int gate = l15 & 3;
    const int unit = c * 16 + w * 4 + (l15 >> 2);
    float bias;
    {
        float bx = (gate == 0) ? bxf[unit] : (gate == 1) ? bxi[unit]
                 : (gate == 2) ? bxg[unit] : bxo[unit];
        float bh = (gate == 0) ? bhf[unit] : (gate == 1) ? bhi[unit]
                 : (gate == 2) ? bhg[unit] : bho[unit];
        bias = bx + bh;
    }
    float cst[4] = {0.f, 0.f, 0.f, 0.f};   // c-state rows quad*4..+3 (quads 0,1 real)
    const int pub = ((l15 & 3) == 0) && (quad < 2);   // publisher lanes
    const int base = lane & ~3;                        // quad-of-4 base lane

    // ---- x-projection shadow: acc_x for step 0 ----
    const size_t xrow = (size_t)(g * 8 + m) * 1024 * 512 + (size_t)quad * 8;
    half8 xf[16];
#pragma unroll
    for (int kk = 0; kk < 16; kk++) xf[kk] = *(const half8*)(XH + xrow + kk * 32);
    float4v accx = {0.f, 0.f, 0.f, 0.f};
#pragma unroll
    for (int kk = 0; kk < 16; kk++) {
        half8 b = *(const half8*)&Xls[w * 16 + l15][kk * 32 + quad * 8];
        accx = __builtin_amdgcn_mfma_f32_16x16x32_f16(xf[kk], b, accx, 0, 0, 0);
    }

    for (int t = 0; t < 1024; t++) {
        // ---- per-thread tagged spin (units 2*tid, 2*tid+1; 64B/pass, 1 RT) ----
        {
            const unsigned long long* hsrc = hws + (size_t)(t & 1) * 16384
                                           + (size_t)g * 2048 + (size_t)tid * 8;
            const unsigned int T = (unsigned)t << 16;
            uint4v q[4];
            for (;;) {
                ld_burst64(hsrc, q);
                unsigned int bad = 0;
#pragma unroll
                for (int j = 0; j < 4; j++)
#pragma unroll
                    for (int e = 0; e < 4; e++)
                        bad |= (q[j][e] ^ T) & 0xFFFF0000u;
                if (!bad) break;
            }
            // repack: q32[2rp]/[2rp+1] = unit 2t rows 2rp/2rp+1;
            //         q32[8+2rp]/[9+2rp] = unit 2t+1 rows 2rp/2rp+1
#pragma unroll
            for (int rp = 0; rp < 4; rp++) {
                unsigned a_lo = q[(2 * rp) >> 2][(2 * rp) & 3];
                unsigned a_hi = q[(2 * rp + 1) >> 2][(2 * rp + 1) & 3];
                unsigned b_lo = q[(8 + 2 * rp) >> 2][(8 + 2 * rp) & 3];
                unsigned b_hi = q[(9 + 2 * rp) >> 2][(9 + 2 * rp) & 3];
                *(unsigned*)&hls[2 * rp][2 * tid]     = (a_lo & 0xFFFFu) | (b_lo << 16);
                *(unsigned*)&hls[2 * rp + 1][2 * tid] = (a_hi & 0xFFFFu) | (b_hi << 16);
            }
        }
        __syncthreads();   // the ONE barrier: hls fully staged before reads

        // ---- h-GEMM: acc = acc_x + h_t @ Wh_slice^T ----
        float4v acca = accx;
        float4v accb = {0.f, 0.f, 0.f, 0.f};
#pragma unroll
        for (int kk = 0; kk < 16; kk += 2) {
            half8 a0 = *(const half8*)&hls[m][kk * 32 + quad * 8];
            half8 a1 = *(const half8*)&hls[m][(kk + 1) * 32 + quad * 8];
            half8 b0 = *(const half8*)&Wls[w * 16 + l15][kk * 32 + quad * 8];
            half8 b1 = *(const half8*)&Wls[w * 16 + l15][(kk + 1) * 32 + quad * 8];
            acca = __builtin_amdgcn_mfma_f32_16x16x32_f16(a0, b0, acca, 0, 0, 0);
            accb = __builtin_amdgcn_mfma_f32_16x16x32_f16(a1, b1, accb, 0, 0, 0);
        }

        // ---- in-wave transpose (quads of 4 lanes) + elementwise, all lanes ----
        float hn[4];
#pragma unroll
        for (int r = 0; r < 4; r++) {
            float pre = acca[r] + accb[r] + bias;
            float fv = __shfl(pre, base + 0, 64);
            float iv = __shfl(pre, base + 1, 64);
            float gv = __shfl(pre, base + 2, 64);
            float ov = __shfl(pre, base + 3, 64);
            cst[r] = sigm(fv) * cst[r] + sigm(iv) * tanh_f(gv);
            hn[r]  = sigm(ov) * tanh_f(cst[r]);
        }

        // ---- immediate per-wave tagged publish (rows quad*4..+3, own unit) ----
        if (pub) {
            unsigned tag = (unsigned)(t + 1) << 16;
            union { _Float16 f; unsigned short u; } v0, v1, v2, v3;
            v0.f = (_Float16)hn[0]; v1.f = (_Float16)hn[1];
            v2.f = (_Float16)hn[2]; v3.f = (_Float16)hn[3];
            unsigned long long q0 = (unsigned long long)(tag | v0.u)
                                  | ((unsigned long long)(tag | v1.u) << 32);
            unsigned long long q1 = (unsigned long long)(tag | v2.u)
                                  | ((unsigned long long)(tag | v3.u) << 32);
            unsigned long long* dst = hws + (size_t)((t + 1) & 1) * 16384
                                    + (size_t)g * 2048 + (size_t)unit * 4
                                    + (size_t)quad * 2;
            st_u64(dst, q0);
            st_u64(dst + 1, q1);
            if (t == 1023) {
#pragma unroll
                for (int r = 0; r < 4; r++)
                    out[(size_t)(g * 8 + quad * 4 + r) * 512 + unit] = hn[r];
            }
        }

        // ---- shadow x-GEMM for step t+1 (off critical path) ----
        int tn = (t < 1023) ? (t + 1) : 0;
        const _Float16* xp = XH + xrow + (size_t)tn * 512;
#pragma unroll
        for (int kk = 0; kk < 16; kk++) xf[kk] = *(const half8*)(xp + kk * 32);
        float4v ax = {0.f, 0.f, 0.f, 0.f};
#pragma unroll
        for (int kk = 0; kk < 16; kk++) {
            half8 b = *(const half8*)&Xls[w * 16 + l15][kk * 32 + quad * 8];
            ax = __builtin_amdgcn_mfma_f32_16x16x32_f16(xf[kk], b, ax, 0, 0, 0);
        }
        accx = ax;
    }
}

// ------------------------------- launcher ----------------------------------
extern "C" void kernel_launch(void* const* d_in, const int* in_sizes, int n_in,
                              void* d_out, int out_size, void* d_ws, size_t ws_size,
                              hipStream_t stream) {
    const float* X   = (const float*)d_in[0];
    const float* Whf = (const float*)d_in[1];  const float* bhf = (const float*)d_in[2];
    const float* Wxf = (const float*)d_in[3];  const float* bxf = (const float*)d_in[4];
    const float* Whi = (const float*)d_in[5];  const float* bhi = (const float*)d_in[6];
    const float* Wxi = (const float*)d_in[7];  const float* bxi = (const float*)d_in[8];
    const float* Whg = (const float*)d_in[9];  const float* bhg = (const float*)d_in[10];
    const float* Wxg = (const float*)d_in[11]; const float* bxg = (const float*)d_in[12];
    const float* Who = (const float*)d_in[13]; const float* bho = (const float*)d_in[14];
    const float* Wxo = (const float*)d_in[15]; const float* bxo = (const float*)d_in[16];

    // ws layout: [0,256KB) tagged h double buffer | [1MB,65MB) XH fp16
    if (ws_size < (size_t)68157440) return;  // need 65 MiB

    char* ws = (char*)d_ws;
    unsigned long long* hws = (unsigned long long*)ws;
    _Float16*           XH  = (_Float16*)(ws + (1 << 20));
    (void)in_sizes; (void)n_in; (void)out_size;

    hipMemsetAsync(d_ws, 0, 262144, stream);
    xcvt<<<16384, 256, 0, stream>>>(X, XH);
    lstm_rec<<<256, 256, 0, stream>>>(Whf, Whi, Whg, Who, Wxf, Wxi, Wxg, Wxo,
                                      bxf, bxi, bxg, bxo, bhf, bhi, bhg, bho,
                                      XH, hws, (float*)d_out);
}

// Round 8
// 4411.008 us; speedup vs baseline: 1.0572x; 1.0018x over previous
//
#include <hip/hip_runtime.h>
#include <cstdint>
#include <cstddef>

// ---------------------------------------------------------------------------
// LSTM  B=64, T=1024, D=H=512.
//   * xcvt: x_seq fp32 -> fp16 in ws (one-time).
//   * lstm_rec: persistent, 256 WGs = 8 batch-groups x 32 column-groups.
//     WG (g,c): batch rows g*8..g*8+7, hidden units c*16..c*16+15.
//     Wh & Wx slices LDS-resident fp16; tagged self-sync h at agent scope.
//     R8 KEY CHANGE: h publish = no-return GLOBAL_ATOMIC_SWAP_X2 sc1.
//       R3/R6/R7 counters showed WRITE_SIZE == exact h traffic (131/262 MB)
//       + ~64KB/step unexplained FETCH: plain sc1 stores write through to
//       HBM and kill the MALL line, so every consumer detect pass missed to
//       HBM (~2 HBM RTs on the critical path per step). Atomics execute AT
//       the MALL -> line stays MALL-resident+dirty, consumer sc1 burst
//       loads hit it. 256KB hws can't evict from 256MB L3.
//     History: sc0-only XCD path hung twice (no architected XCD scope) —
//     permanently dead. Sentinel pre-poll (R6) = +1 serial RT, dead.
// ---------------------------------------------------------------------------

typedef _Float16 half8  __attribute__((ext_vector_type(8)));
typedef _Float16 half4v __attribute__((ext_vector_type(4)));
typedef float    float4v __attribute__((ext_vector_type(4)));
typedef unsigned int uint4v __attribute__((ext_vector_type(4)));

__device__ __forceinline__ float sigm(float x) { return 1.f / (1.f + __expf(-x)); }
__device__ __forceinline__ float tanh_f(float x) { return 2.f / (1.f + __expf(-2.f * x)) - 1.f; }

// agent-scope publish: no-return atomic swap -> executes at MALL, line stays
// resident+dirty there (no HBM write-through, no invalidation)
__device__ __forceinline__ void pub_u64(unsigned long long* p, unsigned long long v) {
    asm volatile("global_atomic_swap_x2 %0, %1, off sc1" :: "v"(p), "v"(v) : "memory");
}

// agent-scope 64B burst load, ONE vmcnt(0) for the whole pass (reads at MALL)
__device__ __forceinline__ void ld_burst64(const void* p, uint4v q[4]) {
    asm volatile(
        "global_load_dwordx4 %[a], %[p], off sc0 sc1\n\t"
        "global_load_dwordx4 %[b], %[p], off offset:16 sc0 sc1\n\t"
        "global_load_dwordx4 %[c], %[p], off offset:32 sc0 sc1\n\t"
        "global_load_dwordx4 %[d], %[p], off offset:48 sc0 sc1\n\t"
        "s_waitcnt vmcnt(0)"
        : [a]"=&v"(q[0]), [b]"=&v"(q[1]), [c]"=&v"(q[2]), [d]"=&v"(q[3])
        : [p]"v"(p) : "memory");
}

// ----------------------------- x fp32 -> fp16 ------------------------------
__global__ __launch_bounds__(256) void xcvt(const float* __restrict__ X,
                                            _Float16* __restrict__ XH) {
    size_t i = ((size_t)blockIdx.x * 256 + threadIdx.x) * 8;
    float4 a = *(const float4*)(X + i);
    float4 b = *(const float4*)(X + i + 4);
    half8 v;
    v[0] = (_Float16)a.x; v[1] = (_Float16)a.y; v[2] = (_Float16)a.z; v[3] = (_Float16)a.w;
    v[4] = (_Float16)b.x; v[5] = (_Float16)b.y; v[6] = (_Float16)b.z; v[7] = (_Float16)b.w;
    *(half8*)(XH + i) = v;
}

// ------------------------------- recurrence --------------------------------
__global__ __launch_bounds__(256, 1) void lstm_rec(
    const float* __restrict__ Whf, const float* __restrict__ Whi,
    const float* __restrict__ Whg, const float* __restrict__ Who,
    const float* __restrict__ Wxf, const float* __restrict__ Wxi,
    const float* __restrict__ Wxg, const float* __restrict__ Wxo,
    const float* __restrict__ bxf, const float* __restrict__ bxi,
    const float* __restrict__ bxg, const float* __restrict__ bxo,
    const float* __restrict__ bhf, const float* __restrict__ bhi,
    const float* __restrict__ bhg, const float* __restrict__ bho,
    const _Float16* __restrict__ XH,        // [64][1024][512] fp16
    unsigned long long* __restrict__ hws,   // tagged h [2][8][512][4] u64, zeroed
    float* __restrict__ out)                // [64][512] fp32
{
    const int blk  = blockIdx.x;
    const int g    = blk & 7;    // batch group
    const int c    = blk >> 3;   // column group 0..31 (units c*16..c*16+15)
    const int tid  = threadIdx.x;
    const int w    = tid >> 6;   // wave 0..3 -> units c*16+w*4 .. +3
    const int lane = tid & 63;
    const int l15  = lane & 15;
    const int quad = lane >> 4;
    const int m    = l15 & 7;    // batch row (A-frag; rows 8..15 dup 0..7)

    // gate-col layout per WG (64 cols): [u0f,u0i,u0g,u0o,u1f,...] per wave
    __shared__ _Float16 Wls[64][520];  // Wh slice in gate-col layout
    __shared__ _Float16 Xls[64][520];  // Wx slice, same layout
    __shared__ _Float16 hls[8][520];   // staged h_t [row][512 units]

    // ---- one-time: weight slices -> LDS fp16 (interleaved layout) ----
    const float* WhSeg[4] = {Whf, Whi, Whg, Who};
    const float* WxSeg[4] = {Wxf, Wxi, Wxg, Wxo};
    for (int e = tid * 4; e < 64 * 512; e += 1024) {
        int row = e >> 9, col = e & 511;
        int gate = row & 3;
        int srow = c * 16 + ((row >> 4) << 2) + ((row >> 2) & 3);
        float4 vh = *(const float4*)(WhSeg[gate] + (size_t)srow * 512 + col);
        float4 vx = *(const float4*)(WxSeg[gate] + (size_t)srow * 512 + col);
        half4v th = {(_Float16)vh.x, (_Float16)vh.y, (_Float16)vh.z, (_Float16)vh.w};
        half4v tx = {(_Float16)vx.x, (_Float16)vx.y, (_Float16)vx.z, (_Float16)vx.w};
        *(half4v*)&Wls[row][col] = th;
        *(half4v*)&Xls[row][col] = tx;
    }
    __syncthreads();

    // ---- per-lane bias (own gate-col): gate = l15&3, unit = c*16+w*4+(l15>>2)
    const int gate = l15 & 3;
    const int unit = c * 16 + w * 4 + (l15 >> 2);
    float bias;
    {
        float bx = (gate == 0) ? bxf[unit] : (gate == 1) ? bxi[unit]
                 : (gate == 2) ? bxg[unit] : bxo[unit];
        float bh = (gate == 0) ? bhf[unit] : (gate == 1) ? bhi[unit]
                 : (gate == 2) ? bhg[unit] : bho[unit];
        bias = bx + bh;
    }
    float cst[4] = {0.f, 0.f, 0.f, 0.f};   // c-state rows quad*4..+3 (quads 0,1 real)
    const int pub = ((l15 & 3) == 0) && (quad < 2);   // publisher lanes
    const int base = lane & ~3;                        // quad-of-4 base lane

    // ---- x-projection shadow: acc_x for step 0 ----
    const size_t xrow = (size_t)(g * 8 + m) * 1024 * 512 + (size_t)quad * 8;
    half8 xf[16];
#pragma unroll
    for (int kk = 0; kk < 16; kk++) xf[kk] = *(const half8*)(XH + xrow + kk * 32);
    float4v accx = {0.f, 0.f, 0.f, 0.f};
#pragma unroll
    for (int kk = 0; kk < 16; kk++) {
        half8 b = *(const half8*)&Xls[w * 16 + l15][kk * 32 + quad * 8];
        accx = __builtin_amdgcn_mfma_f32_16x16x32_f16(xf[kk], b, accx, 0, 0, 0);
    }

    for (int t = 0; t < 1024; t++) {
        // ---- per-thread tagged spin (64B/pass, 1 MALL RT) ----
        {
            const unsigned long long* hsrc = hws + (size_t)(t & 1) * 16384
                                           + (size_t)g * 2048 + (size_t)tid * 8;
            const unsigned int T = (unsigned)t << 16;
            uint4v q[4];
            for (;;) {
                ld_burst64(hsrc, q);
                unsigned int bad = 0;
#pragma unroll
                for (int j = 0; j < 4; j++)
#pragma unroll
                    for (int e = 0; e < 4; e++)
                        bad |= (q[j][e] ^ T) & 0xFFFF0000u;
                if (!bad) break;
            }
            // repack into hls: units 2*tid, 2*tid+1, rows 0..7
#pragma unroll
            for (int rp = 0; rp < 4; rp++) {
                unsigned a_lo = q[(2 * rp) >> 2][(2 * rp) & 3];
                unsigned a_hi = q[(2 * rp + 1) >> 2][(2 * rp + 1) & 3];
                unsigned b_lo = q[(8 + 2 * rp) >> 2][(8 + 2 * rp) & 3];
                unsigned b_hi = q[(9 + 2 * rp) >> 2][(9 + 2 * rp) & 3];
                *(unsigned*)&hls[2 * rp][2 * tid]     = (a_lo & 0xFFFFu) | (b_lo << 16);
                *(unsigned*)&hls[2 * rp + 1][2 * tid] = (a_hi & 0xFFFFu) | (b_hi << 16);
            }
        }
        __syncthreads();   // the ONE barrier: hls fully staged before reads

        // ---- h-GEMM: acc = acc_x + h_t @ Wh_slice^T ----
        float4v acca = accx;
        float4v accb = {0.f, 0.f, 0.f, 0.f};
#pragma unroll
        for (int kk = 0; kk < 16; kk += 2) {
            half8 a0 = *(const half8*)&hls[m][kk * 32 + quad * 8];
            half8 a1 = *(const half8*)&hls[m][(kk + 1) * 32 + quad * 8];
            half8 b0 = *(const half8*)&Wls[w * 16 + l15][kk * 32 + quad * 8];
            half8 b1 = *(const half8*)&Wls[w * 16 + l15][(kk + 1) * 32 + quad * 8];
            acca = __builtin_amdgcn_mfma_f32_16x16x32_f16(a0, b0, acca, 0, 0, 0);
            accb = __builtin_amdgcn_mfma_f32_16x16x32_f16(a1, b1, accb, 0, 0, 0);
        }

        // ---- in-wave transpose (quads of 4 lanes) + elementwise, all lanes ----
        float hn[4];
#pragma unroll
        for (int r = 0; r < 4; r++) {
            float pre = acca[r] + accb[r] + bias;
            float fv = __shfl(pre, base + 0, 64);
            float iv = __shfl(pre, base + 1, 64);
            float gv = __shfl(pre, base + 2, 64);
            float ov = __shfl(pre, base + 3, 64);
            cst[r] = sigm(fv) * cst[r] + sigm(iv) * tanh_f(gv);
            hn[r]  = sigm(ov) * tanh_f(cst[r]);
        }

        // ---- immediate per-wave tagged publish via MALL-resident atomics ----
        if (pub) {
            unsigned tag = (unsigned)(t + 1) << 16;
            union { _Float16 f; unsigned short u; } v0, v1, v2, v3;
            v0.f = (_Float16)hn[0]; v1.f = (_Float16)hn[1];
            v2.f = (_Float16)hn[2]; v3.f = (_Float16)hn[3];
            unsigned long long q0 = (unsigned long long)(tag | v0.u)
                                  | ((unsigned long long)(tag | v1.u) << 32);
            unsigned long long q1 = (unsigned long long)(tag | v2.u)
                                  | ((unsigned long long)(tag | v3.u) << 32);
            unsigned long long* dst = hws + (size_t)((t + 1) & 1) * 16384
                                    + (size_t)g * 2048 + (size_t)unit * 4
                                    + (size_t)quad * 2;
            pub_u64(dst, q0);
            pub_u64(dst + 1, q1);
            if (t == 1023) {
#pragma unroll
                for (int r = 0; r < 4; r++)
                    out[(size_t)(g * 8 + quad * 4 + r) * 512 + unit] = hn[r];
            }
        }

        // ---- shadow x-GEMM for step t+1 (off critical path) ----
        int tn = (t < 1023) ? (t + 1) : 0;
        const _Float16* xp = XH + xrow + (size_t)tn * 512;
#pragma unroll
        for (int kk = 0; kk < 16; kk++) xf[kk] = *(const half8*)(xp + kk * 32);
        float4v ax = {0.f, 0.f, 0.f, 0.f};
#pragma unroll
        for (int kk = 0; kk < 16; kk++) {
            half8 b = *(const half8*)&Xls[w * 16 + l15][kk * 32 + quad * 8];
            ax = __builtin_amdgcn_mfma_f32_16x16x32_f16(xf[kk], b, ax, 0, 0, 0);
        }
        accx = ax;
    }
}

// ------------------------------- launcher ----------------------------------
extern "C" void kernel_launch(void* const* d_in, const int* in_sizes, int n_in,
                              void* d_out, int out_size, void* d_ws, size_t ws_size,
                              hipStream_t stream) {
    const float* X   = (const float*)d_in[0];
    const float* Whf = (const float*)d_in[1];  const float* bhf = (const float*)d_in[2];
    const float* Wxf = (const float*)d_in[3];  const float* bxf = (const float*)d_in[4];
    const float* Whi = (const float*)d_in[5];  const float* bhi = (const float*)d_in[6];
    const float* Wxi = (const float*)d_in[7];  const float* bxi = (const float*)d_in[8];
    const float* Whg = (const float*)d_in[9];  const float* bhg = (const float*)d_in[10];
    const float* Wxg = (const float*)d_in[11]; const float* bxg = (const float*)d_in[12];
    const float* Who = (const float*)d_in[13]; const float* bho = (const float*)d_in[14];
    const float* Wxo = (const float*)d_in[15]; const float* bxo = (const float*)d_in[16];

    // ws layout: [0,256KB) tagged h double buffer | [1MB,65MB) XH fp16
    if (ws_size < (size_t)68157440) return;  // need 65 MiB

    char* ws = (char*)d_ws;
    unsigned long long* hws = (unsigned long long*)ws;
    _Float16*           XH  = (_Float16*)(ws + (1 << 20));
    (void)in_sizes; (void)n_in; (void)out_size;

    hipMemsetAsync(d_ws, 0, 262144, stream);
    xcvt<<<16384, 256, 0, stream>>>(X, XH);
    lstm_rec<<<256, 256, 0, stream>>>(Whf, Whi, Whg, Who, Wxf, Wxi, Wxg, Wxo,
                                      bxf, bxi, bxg, bxo, bhf, bhi, bhg, bho,
                                      XH, hws, (float*)d_out);
}